// Round 6
// baseline (450.419 us; speedup 1.0000x reference)
//
#include <hip/hip_runtime.h>
#include <hip/hip_bf16.h>
#include <math.h>

#define S_LEN 4096
#define DMODEL 768
#define NHEAD 12
#define HDIM 64
#define DFF_ 3072
#define MROWS 8192  // B*S

typedef __bf16 bf16;
typedef __bf16 bf16x4 __attribute__((ext_vector_type(4)));
typedef __bf16 bf16x8 __attribute__((ext_vector_type(8)));
typedef float f32x4 __attribute__((ext_vector_type(4)));
typedef short s16x4 __attribute__((ext_vector_type(4)));
typedef s16x4 frag4;

union F4 { float4 v; float f[4]; };
union U2 { bf16 h[2]; unsigned u; };
union P4 { unsigned u[2]; frag4 v; };

__device__ __forceinline__ void gld_lds16(void* lds, const void* g) {
    __builtin_amdgcn_global_load_lds(
        (const __attribute__((address_space(1))) unsigned int*)g,
        (__attribute__((address_space(3))) unsigned int*)lds, 16, 0, 0);
}

// 16x16x16 bf16 MFMA. A: lane holds A[row=lane&15][k=(lane>>4)*4+j];
// B: B[k=(lane>>4)*4+j][n=lane&15]; C: D[row=(lane>>4)*4+r][col=lane&15].
__device__ __forceinline__ f32x4 mfma16(frag4 a, frag4 b, f32x4 c) {
#if __has_builtin(__builtin_amdgcn_mfma_f32_16x16x16bf16_1k)
    return __builtin_amdgcn_mfma_f32_16x16x16bf16_1k(a, b, c, 0, 0, 0);
#else
    union { frag4 s; bf16x4 h; } ua, ub; ua.s = a; ub.s = b;
    bf16x8 a8 = {ua.h[0], ua.h[1], ua.h[2], ua.h[3],
                 (bf16)0.f, (bf16)0.f, (bf16)0.f, (bf16)0.f};
    bf16x8 b8 = {ub.h[0], ub.h[1], ub.h[2], ub.h[3],
                 (bf16)0.f, (bf16)0.f, (bf16)0.f, (bf16)0.f};
    return __builtin_amdgcn_mfma_f32_16x16x32_bf16(a8, b8, c, 0, 0, 0);
#endif
}

// ---------------- LayerNorm ----------------
template<typename OUT>
__global__ __launch_bounds__(256) void ln_kernel(const float* __restrict__ x,
                                                 const float* __restrict__ g,
                                                 const float* __restrict__ bta,
                                                 OUT* __restrict__ out,
                                                 float* __restrict__ zb) {
    const int row = blockIdx.x;
    const int t = threadIdx.x;
    if (zb && row == 0 && t < 192)
        ((float4*)zb)[t] = make_float4(0.f, 0.f, 0.f, 0.f);
    const float* xr = x + (size_t)row * DMODEL;
    float v0 = xr[t], v1 = xr[t + 256], v2 = xr[t + 512];
    float s = v0 + v1 + v2;
    float ss = v0 * v0 + v1 * v1 + v2 * v2;
    for (int o = 32; o > 0; o >>= 1) {
        s += __shfl_down(s, o, 64);
        ss += __shfl_down(ss, o, 64);
    }
    __shared__ float sm[4], sm2[4];
    const int w = t >> 6, lane = t & 63;
    if (lane == 0) { sm[w] = s; sm2[w] = ss; }
    __syncthreads();
    s = sm[0] + sm[1] + sm[2] + sm[3];
    ss = sm2[0] + sm2[1] + sm2[2] + sm2[3];
    const float mu = s * (1.0f / DMODEL);
    const float var = ss * (1.0f / DMODEL) - mu * mu;
    const float rs = rsqrtf(var + 1e-5f);
    OUT* orow = out + (size_t)row * DMODEL;
    orow[t]       = (OUT)((v0 - mu) * rs * g[t]       + bta[t]);
    orow[t + 256] = (OUT)((v1 - mu) * rs * g[t + 256] + bta[t + 256]);
    orow[t + 512] = (OUT)((v2 - mu) * rs * g[t + 512] + bta[t + 512]);
}

// ---------------- fused weight transpose+convert: all 6 weights, one launch ----------------
__global__ __launch_bounds__(256) void wtrans_all_kernel(
    const float* __restrict__ Wq, const float* __restrict__ Wk,
    const float* __restrict__ Wv, const float* __restrict__ Wo,
    const float* __restrict__ W1, const float* __restrict__ W2,
    bf16* __restrict__ Wqt, bf16* __restrict__ Wkt, bf16* __restrict__ Wvt,
    bf16* __restrict__ Wot, bf16* __restrict__ W1t, bf16* __restrict__ W2t) {
    int t = blockIdx.x;
    const float* W; bf16* Wt; int K, N;
    if      (t < 144)  { W = Wq; Wt = Wqt; K = 768;  N = 768;  }
    else if (t < 288)  { W = Wk; Wt = Wkt; K = 768;  N = 768;  t -= 144; }
    else if (t < 432)  { W = Wv; Wt = Wvt; K = 768;  N = 768;  t -= 288; }
    else if (t < 576)  { W = Wo; Wt = Wot; K = 768;  N = 768;  t -= 432; }
    else if (t < 1152) { W = W1; Wt = W1t; K = 768;  N = 3072; t -= 576; }
    else               { W = W2; Wt = W2t; K = 3072; N = 768;  t -= 1152; }
    const int nx = N >> 6;
    const int n0 = (t % nx) * 64, k0 = (t / nx) * 64;

    __shared__ float tile[64][65];
    const int tid = threadIdx.x;
    const int lr = tid >> 4, lc = (tid & 15) << 2;
#pragma unroll
    for (int i = 0; i < 4; ++i) {
        const int r = lr + i * 16;
        F4 w; w.v = *(const float4*)&W[(size_t)(k0 + r) * N + n0 + lc];
#pragma unroll
        for (int j = 0; j < 4; ++j) tile[r][lc + j] = w.f[j];
    }
    __syncthreads();
#pragma unroll
    for (int i = 0; i < 4; ++i) {
        const int n = lr + i * 16;
        bf16x4 o;
#pragma unroll
        for (int j = 0; j < 4; ++j) o[j] = (bf16)tile[lc + j][n];
        *(bf16x4*)&Wt[(size_t)(n0 + n) * K + k0 + lc] = o;
    }
}

// ---------------- V transpose: vb[token][col] -> vbt[(b,h)][d][key] (plain V^T) ----------------
__global__ __launch_bounds__(256) void vtrans_kernel(const bf16* __restrict__ vb,
                                                     bf16* __restrict__ vbt) {
    const int kt = blockIdx.x, h = blockIdx.y, b = blockIdx.z;
    __shared__ bf16 tile[64][65];
    const int t = threadIdx.x;
    const int kl = t >> 2, ds = (t & 3) * 16;
    const bf16* src = vb + (size_t)(b * S_LEN + kt * 64 + kl) * DMODEL + h * HDIM + ds;
    *(bf16x8*)&tile[kl][ds]     = *(const bf16x8*)src;
    *(bf16x8*)&tile[kl][ds + 8] = *(const bf16x8*)(src + 8);
    __syncthreads();
    const int d = t >> 2;
    bf16* drow = vbt + (size_t)((b * NHEAD + h) * HDIM + d) * S_LEN + kt * 64;
#pragma unroll
    for (int c = 0; c < 2; ++c) {
        const int k0 = (t & 3) * 16 + c * 8;
        bf16x8 o;
#pragma unroll
        for (int j = 0; j < 8; ++j) o[j] = tile[k0 + j][d];
        *(bf16x8*)(drow + k0) = o;
    }
}

// ---------------- bf16 MFMA GEMM, MT x 128 tile, BK=64, XCD-swizzled ----------------
// MFMA operands SWAPPED (mfma(b,a,acc) -> C^T fragment layout): each lane's 4
// acc elements are 4 CONSECUTIVE output columns -> fully vectorized epilogue.
template<int MT, bool RELU, bool RES, bool OUT_BF16>
__global__ __launch_bounds__(256) void mgemm_kernel(
    const bf16* __restrict__ A,
    const bf16* __restrict__ Wt0, const float* __restrict__ bias0, void* __restrict__ C0,
    const bf16* __restrict__ Wt1, const float* __restrict__ bias1, void* __restrict__ C1,
    const bf16* __restrict__ Wt2, const float* __restrict__ bias2, void* __restrict__ C2,
    const float* __restrict__ R, int M, int N, int K, int Kloop,
    int koff0, int koff1, int koff2,
    float sc0, float sc1, float sc2) {
    const bf16* Wt = Wt0; const float* bias = bias0; void* C = C0; float sc = sc0; int koff = koff0;
    if (blockIdx.z == 1) { Wt = Wt1; bias = bias1; C = C1; sc = sc1; koff = koff1; }
    if (blockIdx.z == 2) { Wt = Wt2; bias = bias2; C = C2; sc = sc2; koff = koff2; }

    // T1: XCD-aware bijective tile remap ((gx*gy) % 8 == 0 for all launches).
    const int gx = gridDim.x;
    const int nwg = gx * gridDim.y;
    const int chunk = nwg >> 3;
    int lid = blockIdx.y * gx + blockIdx.x;
    lid = (lid & 7) * chunk + (lid >> 3);
    const int row0 = (lid / gx) * MT, col0 = (lid % gx) * 128;

    constexpr int NI = (MT == 128) ? 4 : 2;
    __shared__ bf16 As[2][MT * 32];
    __shared__ bf16 Bs[2][128 * 32];

    const int tid = threadIdx.x;
    const int wave = tid >> 6, lane = tid & 63;
    const int wr = (MT == 128) ? (wave >> 1) * 64 : 0;
    const int wc = (MT == 128) ? (wave & 1) * 64 : wave * 32;
    const int mrow = lane & 15, kq = (lane >> 4) * 8;

    const int st_row = (lane >> 2);
    const int st_off = (lane & 3) * 16;

    f32x4 acc[4][NI] = {};

    const char* Ab = (const char*)(A + (size_t)row0 * K + koff);
    const char* Bb = (const char*)(Wt + (size_t)col0 * K + koff);
    const size_t strideA = (size_t)K * 2;

    for (int k0 = 0; k0 < Kloop; k0 += 64) {
#pragma unroll
        for (int s = 0; s < 2; ++s) {
            const int kk = k0 + s * 32;
            if (MT == 128) {
#pragma unroll
                for (int issue = 0; issue < 2; ++issue) {
                    const int r = wave * 32 + issue * 16 + st_row;
                    gld_lds16((char*)As[s] + (wave * 32 + issue * 16) * 64,
                              Ab + (size_t)r * strideA + kk * 2 + st_off);
                }
            } else {
                const int r = wave * 16 + st_row;
                gld_lds16((char*)As[s] + (wave * 16) * 64,
                          Ab + (size_t)r * strideA + kk * 2 + st_off);
            }
#pragma unroll
            for (int issue = 0; issue < 2; ++issue) {
                const int r = wave * 32 + issue * 16 + st_row;
                gld_lds16((char*)Bs[s] + (wave * 32 + issue * 16) * 64,
                          Bb + (size_t)r * strideA + kk * 2 + st_off);
            }
        }
        __syncthreads();
#pragma unroll
        for (int s = 0; s < 2; ++s) {
            bf16x8 af[4], bfr[NI];
#pragma unroll
            for (int mi = 0; mi < 4; ++mi)
                af[mi] = *(const bf16x8*)&As[s][(wr + mi * 16 + mrow) * 32 + kq];
#pragma unroll
            for (int ni = 0; ni < NI; ++ni)
                bfr[ni] = *(const bf16x8*)&Bs[s][(wc + ni * 16 + mrow) * 32 + kq];
#pragma unroll
            for (int mi = 0; mi < 4; ++mi)
#pragma unroll
                for (int ni = 0; ni < NI; ++ni)
                    acc[mi][ni] = __builtin_amdgcn_mfma_f32_16x16x32_bf16(
                        bfr[ni], af[mi], acc[mi][ni], 0, 0, 0);   // SWAPPED: C^T frag
        }
        __syncthreads();
    }

    // epilogue: acc[mi][ni][r] = C[row0+wr+mi*16+mrow][col0+wc+ni*16+quad*4+r]
    const int quad = lane >> 4;
#pragma unroll
    for (int ni = 0; ni < NI; ++ni) {
        const int col = col0 + wc + ni * 16 + quad * 4;
        F4 bv4; bv4.v = *(const float4*)&bias[col];
#pragma unroll
        for (int mi = 0; mi < 4; ++mi) {
            const int row = row0 + wr + mi * 16 + mrow;
            F4 o;
#pragma unroll
            for (int r = 0; r < 4; ++r) o.f[r] = acc[mi][ni][r] + bv4.f[r];
            if (RES) {
                F4 rr; rr.v = *(const float4*)&R[(size_t)row * N + col];
#pragma unroll
                for (int r = 0; r < 4; ++r) o.f[r] += rr.f[r];
            }
#pragma unroll
            for (int r = 0; r < 4; ++r) {
                o.f[r] *= sc;
                if (RELU) o.f[r] = fmaxf(o.f[r], 0.0f);
            }
            if (OUT_BF16) {
                bf16x4 ob;
#pragma unroll
                for (int r = 0; r < 4; ++r) ob[r] = (bf16)o.f[r];
                *(bf16x4*)&((bf16*)C)[(size_t)row * N + col] = ob;
            } else {
                *(float4*)&((float*)C)[(size_t)row * N + col] = o.v;
            }
        }
    }
}

// ---------------- Transposed-S MFMA flash attention, DMA-staged K/V ----------------
// r0 schedule (proven fastest) with staging replaced by global_load_lds DMA:
//   K: LDS [64 key][128B d-row], source chunk-swizzled c^(key&7) (m173 pattern)
//   V: LDS [64 d][128B key-row], from plain-V^T vbt, source chunk c^(d&7)
// Reads apply the matching XOR at HIP level (no asm, no fences -> compiler
// schedules freely; r3's lgkmcnt-fence loss avoided). Bank check (32-lane
// phase model that matches r0's measured 0 conflicts): <=2 lanes/bank = free.
// l-fusion via CONSTANT all-ones A fragment (no ones row). T5 setprio, T13
// defer-max kept. grid (32,H,B) = 768 paired-uniform blocks, dbuf, 1 barrier/iter.
__global__ __launch_bounds__(256) void mattn_kernel(
    const bf16* __restrict__ Q, const bf16* __restrict__ K,
    const bf16* __restrict__ Vt, const int* __restrict__ amask,
    bf16* __restrict__ O) {
    const int bx = blockIdx.x, h = blockIdx.y, b = blockIdx.z;

    __shared__ bf16 Ks[2][4096];   // [buf] 8KB: 64 key x 128B, chunk-swizzled
    __shared__ bf16 Vs[2][4096];   // [buf] 8KB: 64 d x 128B, chunk-swizzled
    __shared__ bf16 Os[64][68];    // epilogue bounce
    __shared__ float mk[2][64];
    __shared__ int flagv[2];

    const int tid = threadIdx.x;
    const int wave = tid >> 6, lane = tid & 63;
    const int l = lane & 15, quad = lane >> 4;
    const float NEG_INF = -__builtin_huge_valf();

    // DMA granule maps: 16B granules, 512/tile, 2 issues/thread.
    // granule g: row = g>>3 (key for K, d for V), position-chunk p = g&7;
    // source fetches chunk p^(row&7) -> LDS position p holds chunk p^(row&7).
    const int g1 = 256 + tid;
    const int rw0 = tid >> 3, pc0 = tid & 7;
    const int rw1 = g1 >> 3,  pc1 = g1 & 7;
    const int koff0 = rw0 * DMODEL + ((pc0 ^ (rw0 & 7)) << 3);
    const int koff1 = rw1 * DMODEL + ((pc1 ^ (rw1 & 7)) << 3);
    const int voff0 = rw0 * S_LEN + ((pc0 ^ (rw0 & 7)) << 3);
    const int voff1 = rw1 * S_LEN + ((pc1 ^ (rw1 & 7)) << 3);

    const bf16* Kbase = K + (size_t)b * S_LEN * DMODEL + h * HDIM;
    const bf16* Vtb = Vt + (size_t)((b * NHEAD + h) * HDIM) * S_LEN;

    // swizzled read offsets: reader wanting chunk c of row reads position c^(row&7)
    const int sw = (l & 7) << 4;                       // rows are mi*16+l / di*16+l
    const int krd0 = l * 128 + ((quad << 4) ^ sw);     // kf0: d-chunk = quad
    const int krd1 = l * 128 + (((4 + quad) << 4) ^ sw); // kf1: d-chunk = 4+quad

    P4 onesu; onesu.u[0] = 0x3F803F80u; onesu.u[1] = 0x3F803F80u;
    const frag4 onesA = onesu.v;

#pragma unroll 1
    for (int pass = 0; pass < 2; ++pass) {
        const int qt = pass ? bx : (63 - bx);

        const bf16* Qb = Q + (size_t)(b * S_LEN + qt * 64 + wave * 16 + l) * DMODEL + h * HDIM;
        const bf16x8 qf0 = *(const bf16x8*)(Qb + quad * 8);
        const bf16x8 qf1 = *(const bf16x8*)(Qb + 32 + quad * 8);

        float m_run = NEG_INF;
        f32x4 acc[4] = {};   // acc[di][r] = O[query wave*16+l][d di*16+quad*4+r]... (O^T frag)
        f32x4 acc_l = {};

        // ---- stage tile 0 (DMA) + mask; prior-pass LDS use all drained by its barriers
        {
            char* kd = (char*)Ks[0] + wave * 1024;
            char* vd = (char*)Vs[0] + wave * 1024;
            gld_lds16(kd,        Kbase + koff0);
            gld_lds16(kd + 4096, Kbase + koff1);
            gld_lds16(vd,        Vtb + voff0);
            gld_lds16(vd + 4096, Vtb + voff1);
            if (wave == 0) {
                int mv0 = amask[b * S_LEN + lane];
                mk[0][lane] = mv0 ? 0.0f : NEG_INF;
                unsigned long long bal = __ballot(mv0 != 0);
                if (lane == 0) flagv[0] = (bal == ~0ULL);
            }
        }
        __syncthreads();   // drains DMA (vmcnt) + mk visible
        int buf = 0;
        int mv = 1;

        for (int kt = 0; kt <= qt; ++kt) {
            const bool more = (kt < qt);
            if (more) {
                const bf16* kg = Kbase + (size_t)(kt + 1) * 64 * DMODEL;
                const bf16* vg = Vtb + (kt + 1) * 64;
                const int nb = buf ^ 1;
                char* kd = (char*)Ks[nb] + wave * 1024;
                char* vd = (char*)Vs[nb] + wave * 1024;
                gld_lds16(kd,        kg + koff0);
                gld_lds16(kd + 4096, kg + koff1);
                gld_lds16(vd,        vg + voff0);
                gld_lds16(vd + 4096, vg + voff1);
                if (wave == 0) mv = amask[b * S_LEN + (kt + 1) * 64 + lane];
            }

            const int allv = flagv[buf];
            const char* Ksb = (const char*)Ks[buf];
            const char* Vsb = (const char*)Vs[buf];
            f32x4 sreg[4] = {};
            __builtin_amdgcn_s_setprio(1);
#pragma unroll
            for (int mi = 0; mi < 4; ++mi) {
                bf16x8 kf0 = *(const bf16x8*)(Ksb + mi * 2048 + krd0);
                bf16x8 kf1 = *(const bf16x8*)(Ksb + mi * 2048 + krd1);
                sreg[mi] = __builtin_amdgcn_mfma_f32_16x16x32_bf16(kf0, qf0, sreg[mi], 0, 0, 0);
                sreg[mi] = __builtin_amdgcn_mfma_f32_16x16x32_bf16(kf1, qf1, sreg[mi], 0, 0, 0);
            }
            __builtin_amdgcn_s_setprio(0);
            if (!allv) {
#pragma unroll
                for (int mi = 0; mi < 4; ++mi) {
                    F4 m4; m4.v = *(const float4*)&mk[buf][mi * 16 + quad * 4];
#pragma unroll
                    for (int r = 0; r < 4; ++r) sreg[mi][r] += m4.f[r];
                }
            }
            if (kt == qt) {
#pragma unroll
                for (int mi = 0; mi < 4; ++mi)
#pragma unroll
                    for (int r = 0; r < 4; ++r)
                        if (mi * 16 + quad * 4 + r > wave * 16 + l)
                            sreg[mi][r] = NEG_INF;
            }

            // online softmax (15 max + 2 shfl); T13 defer-max gate.
            float mloc = sreg[0][0];
#pragma unroll
            for (int mi = 0; mi < 4; ++mi)
#pragma unroll
                for (int r = 0; r < 4; ++r) mloc = fmaxf(mloc, sreg[mi][r]);
            mloc = fmaxf(mloc, __shfl_xor(mloc, 16, 64));
            mloc = fmaxf(mloc, __shfl_xor(mloc, 32, 64));
            if (__any(mloc > m_run + 8.0f)) {
                const float mn = fmaxf(m_run, mloc);
                const float alpha = __builtin_amdgcn_exp2f(m_run - mn);
                m_run = mn;
#pragma unroll
                for (int di = 0; di < 4; ++di)
#pragma unroll
                    for (int r = 0; r < 4; ++r) acc[di][r] *= alpha;
#pragma unroll
                for (int r = 0; r < 4; ++r) acc_l[r] *= alpha;
            }
#pragma unroll
            for (int mi = 0; mi < 4; ++mi)
#pragma unroll
                for (int r = 0; r < 4; ++r)
                    sreg[mi][r] = __builtin_amdgcn_exp2f(sreg[mi][r] - m_run);

            // pack P^T (keys mi*16+quad*4+{0..3}, query l) = PV B-operand
            unsigned pk[4][2];
#pragma unroll
            for (int mi = 0; mi < 4; ++mi) {
                U2 w0; w0.h[0] = (bf16)sreg[mi][0]; w0.h[1] = (bf16)sreg[mi][1];
                U2 w1; w1.h[0] = (bf16)sreg[mi][2]; w1.h[1] = (bf16)sreg[mi][3];
                pk[mi][0] = w0.u; pk[mi][1] = w1.u;
            }

            // O^T += V^T · P^T ; const-ones A-fragment accumulates l.
            __builtin_amdgcn_s_setprio(1);
#pragma unroll
            for (int mi = 0; mi < 4; ++mi) {
                P4 pb; pb.u[0] = pk[mi][0]; pb.u[1] = pk[mi][1];
                const int vb_mi = (((mi << 5) | (quad << 3)) ^ sw);  // key-chunk swz
#pragma unroll
                for (int di = 0; di < 4; ++di) {
                    frag4 va = *(const frag4*)(Vsb + di * 2048 + l * 128 + vb_mi);
                    acc[di] = mfma16(va, pb.v, acc[di]);
                }
                acc_l = mfma16(onesA, pb.v, acc_l);
            }
            __builtin_amdgcn_s_setprio(0);

            if (more && wave == 0) {
                const int nb = buf ^ 1;
                mk[nb][lane] = mv ? 0.0f : NEG_INF;
                unsigned long long bal = __ballot(mv != 0);
                if (lane == 0) flagv[nb] = (bal == ~0ULL);
            }
            __syncthreads();
            buf ^= 1;
        }

        // l lives in acc_l[0] of lane (quad0, col==query); broadcast via shfl.
        const float l_fin = __shfl(acc_l[0], l, 64);
        const float rinv = 1.0f / l_fin;
#pragma unroll
        for (int mi = 0; mi < 4; ++mi) {
            U2 w0; w0.h[0] = (bf16)(acc[mi][0] * rinv); w0.h[1] = (bf16)(acc[mi][1] * rinv);
            U2 w1; w1.h[0] = (bf16)(acc[mi][2] * rinv); w1.h[1] = (bf16)(acc[mi][3] * rinv);
            *(unsigned*)&Os[wave * 16 + l][mi * 16 + quad * 4]     = w0.u;
            *(unsigned*)&Os[wave * 16 + l][mi * 16 + quad * 4 + 2] = w1.u;
        }
        __syncthreads();
        {
            const int orow = tid >> 2, oseg = (tid & 3) * 16;
            bf16* Og = O + (size_t)(b * S_LEN + qt * 64 + orow) * DMODEL + h * HDIM + oseg;
            *(bf16x8*)Og       = *(const bf16x8*)&Os[orow][oseg];
            *(bf16x8*)(Og + 8) = *(const bf16x8*)&Os[orow][oseg + 8];
        }
        __syncthreads();   // Os reads done before next pass's epilogue reuse
    }
}

// ---------------- launcher ----------------
extern "C" void kernel_launch(void* const* d_in, const int* in_sizes, int n_in,
                              void* d_out, int out_size, void* d_ws, size_t ws_size,
                              hipStream_t stream) {
    const float* x     = (const float*)d_in[0];
    const int*   amask = (const int*)  d_in[1];
    const float* ln1_g = (const float*)d_in[2];
    const float* ln1_b = (const float*)d_in[3];
    const float* ln2_g = (const float*)d_in[4];
    const float* ln2_b = (const float*)d_in[5];
    const float* Wq = (const float*)d_in[6];  const float* bq = (const float*)d_in[7];
    const float* Wk = (const float*)d_in[8];  const float* bk = (const float*)d_in[9];
    const float* Wv = (const float*)d_in[10]; const float* bv = (const float*)d_in[11];
    const float* Wo = (const float*)d_in[12]; const float* bo = (const float*)d_in[13];
    const float* W1 = (const float*)d_in[14]; const float* b1 = (const float*)d_in[15];
    const float* W2 = (const float*)d_in[16]; const float* b2 = (const float*)d_in[17];
    float* out = (float*)d_out;

    char* ws = (char*)d_ws;
    const size_t WSML = (size_t)DMODEL * DMODEL * 2;
    const size_t WBIG = (size_t)DMODEL * DFF_ * 2;
    bf16* Wqt = (bf16*)(ws + 0 * WSML);
    bf16* Wkt = (bf16*)(ws + 1 * WSML);
    bf16* Wvt = (bf16*)(ws + 2 * WSML);
    bf16* Wot = (bf16*)(ws + 3 * WSML);
    bf16* W1t = (bf16*)(ws + 4 * WSML);
    bf16* W2t = (bf16*)(ws + 4 * WSML + WBIG);
    char* act = ws + 4 * WSML + 2 * WBIG;

    const size_t HB = (size_t)MROWS * DMODEL * 2;   // bf16 activation (12.6 MB)
    const size_t FB = (size_t)MROWS * DMODEL * 4;   // fp32 activation (25.2 MB)
    bf16*  h    = (bf16*)(act);            // LN1 out; later ctx; later h2
    bf16*  qb   = (bf16*)(act + HB);
    bf16*  kb   = (bf16*)(act + 2 * HB);
    bf16*  vb   = (bf16*)(act + 3 * HB);
    bf16*  ctx  = h;
    float* x1   = (float*)(act + 4 * HB);
    bf16*  f    = (bf16*)(act + 4 * HB + FB);      // FF1 out (50.3 MB)
    bf16*  h2   = h;
    bf16*  vbt  = f;   // V^T buffer aliases f (f written at step 6, vbt dead by then)

    const float SCL = 0.125f * 1.44269504089f;  // 1/sqrt(64) * log2(e), folded into Q

    // 0. fused weight transpose+convert (one launch, 1728 tiles)
    wtrans_all_kernel<<<1728, 256, 0, stream>>>(Wq, Wk, Wv, Wo, W1, W2,
                                                Wqt, Wkt, Wvt, Wot, W1t, W2t);

    // 1. LN1 -> h (bf16)
    ln_kernel<bf16><<<MROWS, 256, 0, stream>>>(x, ln1_g, ln1_b, h, nullptr);
    // 2. QKV fused, bf16 out; Q pre-scaled by SCL  (1152 blocks)
    mgemm_kernel<128, false, false, true><<<dim3(DMODEL / 128, MROWS / 128, 3), 256, 0, stream>>>(
        h, Wqt, bq, qb, Wkt, bk, kb, Wvt, bv, vb, nullptr,
        MROWS, DMODEL, DMODEL, DMODEL, 0, 0, 0, SCL, 1.0f, 1.0f);
    // 2b. V -> V^T (per-head [d][key]) for attention's DMA staging  (1536 blocks)
    vtrans_kernel<<<dim3(S_LEN / 64, NHEAD, 2), 256, 0, stream>>>(vb, vbt);
    // 3. flash attention -> ctx (bf16)  (768 paired-uniform blocks)
    mattn_kernel<<<dim3(32, NHEAD, 2), 256, 0, stream>>>(qb, kb, vbt, amask, ctx);
    // 4. out proj + residual(x) -> x1 (fp32)  (MT=64: 768 blocks)
    mgemm_kernel<64, false, true, false><<<dim3(DMODEL / 128, MROWS / 64, 1), 256, 0, stream>>>(
        ctx, Wot, bo, x1, Wot, bo, x1, Wot, bo, x1, x,
        MROWS, DMODEL, DMODEL, DMODEL, 0, 0, 0, 1.0f, 1.0f, 1.0f);
    // 5. LN2 -> h2 (bf16)
    ln_kernel<bf16><<<MROWS, 256, 0, stream>>>(x1, ln2_g, ln2_b, h2, nullptr);
    // 6. FF1 + relu -> f (bf16)  (1536 blocks)
    mgemm_kernel<128, true, false, true><<<dim3(DFF_ / 128, MROWS / 128, 1), 256, 0, stream>>>(
        h2, W1t, b1, f, W1t, b1, f, W1t, b1, f, nullptr,
        MROWS, DFF_, DMODEL, DMODEL, 0, 0, 0, 1.0f, 1.0f, 1.0f);
    // 7. FF2 full-K, MT=64 (768 blocks): out = f@W2 + b2 + x1, fp32 direct.
    mgemm_kernel<64, false, true, false><<<dim3(DMODEL / 128, MROWS / 64, 1), 256, 0, stream>>>(
        f, W2t, b2, out, W2t, b2, out, W2t, b2, out, x1,
        MROWS, DMODEL, DFF_, DFF_, 0, 0, 0, 1.0f, 1.0f, 1.0f);
}